// Round 18
// baseline (201.860 us; speedup 1.0000x reference)
//
#include <hip/hip_runtime.h>
#include <hip/hip_cooperative_groups.h>
#include <hip/hip_bf16.h>
#include <hip/hip_fp16.h>
#include <math.h>

namespace cg = cooperative_groups;

#define BATCH 64
#define LAT   256
#define DVOX  64
#define VOX   (DVOX*DVOX*DVOX)   // 262144

typedef __attribute__((ext_vector_type(8))) short short8;
typedef __attribute__((ext_vector_type(4))) float f32x4;
typedef unsigned uint32x4 __attribute__((ext_vector_type(4), aligned(4)));

#define EROW 264   // enc-LDS row stride in shorts (256 + 8 pad -> 528 B)

__device__ __forceinline__ float zlerp(unsigned e, float fz) {
    __half2 h = *reinterpret_cast<__half2*>(&e);
    float2 f = __half22float2(h);
    return f.x + (f.y - f.x) * fz;
}

// ============================ FUSED KERNEL =================================
// Phase 0: enc->bf16 into LDS. Phase A: R12 3-deep register-pipelined GEMM,
// 2 tiles/block. grid.sync(). Phase B: R12 render, 8 tiles/block (fixed
// batch = bid&63 -> volume L2-resident). 512 blocks x 256 thr, 33.8 KB LDS,
// (256,2) -> exactly 2 blocks/CU co-resident (cooperative-valid).
__global__ __launch_bounds__(256, 2) void fused_kernel(
        const float* __restrict__ enc,     // [64,256]
        const float* __restrict__ W,       // [256, 262144]
        const float* __restrict__ bias,    // [262144]
        const float* __restrict__ angles,  // [64,3]
        __half* __restrict__ vox,          // [64, 262144] ws
        float* __restrict__ out) {         // [64,1,64,64]
    __shared__ __align__(16) unsigned char smem[BATCH * EROW * 2];  // 33792 B

    int bid  = blockIdx.x;                 // 0..511
    int tid  = threadIdx.x;
    int wave = tid >> 6, lane = tid & 63;
    int l15  = lane & 15, l4 = lane >> 4;

    // ---------------- phase 0: enc -> bf16 in LDS --------------------------
    unsigned short* eL = (unsigned short*)smem;
    for (int idx = tid; idx < BATCH * LAT; idx += 256) {
        int row = idx >> 8, k = idx & 255;
        __hip_bfloat16 h = __float2bfloat16(enc[idx]);
        eL[row * EROW + k] = *reinterpret_cast<unsigned short*>(&h);
    }
    __syncthreads();

    // ---------------- phase A: GEMM (2 tiles of 256 cols) ------------------
    const unsigned short* ap = eL + l15 * EROW + l4 * 8;

#pragma unroll 1
    for (int rep = 0; rep < 2; ++rep) {
        int n0 = (bid + rep * 512) * 256;
        int n4 = n0 + wave * 64 + 4 * l15;
        const float* wp = W + (size_t)(l4 * 8) * VOX + n4;

        f32x4 acc[4][4];
#pragma unroll
        for (int t = 0; t < 4; ++t)
#pragma unroll
            for (int mt = 0; mt < 4; ++mt) acc[t][mt] = (f32x4){0.f, 0.f, 0.f, 0.f};

        float4 w0[8], w1[8], w2[8];
        auto loadbuf = [&](float4* buf, int kb) {
            const float* q = wp + (size_t)kb * VOX;
#pragma unroll
            for (int j = 0; j < 8; ++j)
                buf[j] = *(const float4*)(q + (size_t)j * VOX);
        };
        auto consume = [&](const float4* w, int kb) {
            short8 a[4];
#pragma unroll
            for (int mt = 0; mt < 4; ++mt)
                a[mt] = *(const short8*)(ap + mt * 16 * EROW + kb);  // LDS b128
            short8 bf[4];
#pragma unroll
            for (int t = 0; t < 4; ++t) {
                unsigned bw[4];
#pragma unroll
                for (int dw = 0; dw < 4; ++dw) {
                    unsigned u0 = __float_as_uint(((const float*)&w[2 * dw])[t])     + 0x8000u;
                    unsigned u1 = __float_as_uint(((const float*)&w[2 * dw + 1])[t]) + 0x8000u;
                    bw[dw] = __builtin_amdgcn_perm(u1, u0, 0x07060302u);
                }
                bf[t] = *reinterpret_cast<short8*>(bw);
            }
#pragma unroll
            for (int t = 0; t < 4; ++t)
#pragma unroll
                for (int mt = 0; mt < 4; ++mt)
                    acc[t][mt] = __builtin_amdgcn_mfma_f32_16x16x32_bf16(a[mt], bf[t], acc[t][mt], 0, 0, 0);
        };

        // 3-deep register pipeline over 8 k-blocks (R12, proven)
        loadbuf(w0, 0);
        loadbuf(w1, 32);
        loadbuf(w2, 64);  consume(w0, 0);
        loadbuf(w0, 96);  consume(w1, 32);
        loadbuf(w1, 128); consume(w2, 64);
        loadbuf(w2, 160); consume(w0, 96);
        loadbuf(w0, 192); consume(w1, 128);
        loadbuf(w1, 224); consume(w2, 160);
        consume(w0, 192);
        consume(w1, 224);

        float4 bv = *(const float4*)(bias + n4);
#pragma unroll
        for (int mt = 0; mt < 4; ++mt) {
#pragma unroll
            for (int r = 0; r < 4; ++r) {
                int b = mt * 16 + l4 * 4 + r;
                float s[4];
#pragma unroll
                for (int t = 0; t < 4; ++t) {
                    float x = acc[t][mt][r] + ((const float*)&bv)[t];
                    float v = 1.f / (1.f + __expf(-x));   // sigmoid
                    v = v * v; v = v * v; v = v * v;      // ^8
                    s[t] = v;
                }
                __half2 h01 = __floats2half2_rn(s[0], s[1]);
                __half2 h23 = __floats2half2_rn(s[2], s[3]);
                uint2 pk;
                pk.x = *reinterpret_cast<unsigned*>(&h01);
                pk.y = *reinterpret_cast<unsigned*>(&h23);
                *reinterpret_cast<uint2*>(vox + (size_t)b * VOX + n4) = pk;
            }
        }
    }

    // ---------------- render setup (pre-sync, register-only) ---------------
    int b = bid & 63;
    float ax = angles[b*3+0], ay = angles[b*3+1], az = angles[b*3+2];
    float cx = cosf(ax), sx = sinf(ax);
    float cy = cosf(ay), sy = sinf(ay);
    float cz = cosf(az), sz = sinf(az);
    float R0 = cz*cy, R1 = cz*sy*sx - sz*cx, R2 = cz*sy*cx + sz*sx;
    float R3 = sz*cy, R4 = sz*sy*sx + cz*cx, R5 = sz*sy*cx - cz*sx;
    float R6 = -sy,   R7 = cy*sx,            R8 = cy*cx;

    cg::this_grid().sync();                // all vox written & visible

    // ---------------- phase B: render (8 tiles, batch b) -------------------
    unsigned* sV = (unsigned*)smem;                       // 17408 B
    float (*sT)[64] = (float(*)[64])(smem + 17408);       // 1024 B
    float (*sE)[64] = (float(*)[64])(smem + 18432);       // 1024 B

    int pix = tid & 63, seg = tid >> 6;
    int rx = tid >> 4, ry = tid & 15;
    const float c = (DVOX - 1) * 0.5f;
    float hwx = 3.5f * (fabsf(R0) + fabsf(R1) + fabsf(R2)) + 1e-3f;
    float hwy = 3.5f * (fabsf(R3) + fabsf(R4) + fabsf(R5)) + 1e-3f;
    float hwz = 3.5f * (fabsf(R6) + fabsf(R7) + fabsf(R8)) + 1e-3f;
    const unsigned short* V = (const unsigned short*)vox + (size_t)b * VOX;

#pragma unroll 1
    for (int r = 0; r < 8; ++r) {
        int tile = (bid + 512 * r) >> 6;   // (bid+512r)&63 == b
        int i0 = (tile >> 3) * 8, j0 = (tile & 7) * 8;
        int i = i0 + (pix >> 3);
        int j = j0 + (pix & 7);

        float di = (float)i - c, dj = (float)j - c;
        float xb = fmaf(R0, di, fmaf(R1, dj, c));
        float yb = fmaf(R3, di, fmaf(R4, dj, c));
        float zb = fmaf(R6, di, fmaf(R7, dj, c));
        float dic = (float)i0 + 3.5f - c;
        float djc = (float)j0 + 3.5f - c;

        unsigned d[9];
        int xlo_n, ylo_n, zlo_n, s_n;
        auto bbox = [&](int ch) {
            float dkc = (float)(ch * 8) + 3.5f - c;
            float xc = fmaf(R0, dic, fmaf(R1, djc, fmaf(R2, dkc, c)));
            float yc = fmaf(R3, dic, fmaf(R4, djc, fmaf(R5, dkc, c)));
            float zc = fmaf(R6, dic, fmaf(R7, djc, fmaf(R8, dkc, c)));
            xlo_n = (int)floorf(xc - hwx);
            ylo_n = (int)floorf(yc - hwy);
            zlo_n = (int)floorf(zc - hwz);
            s_n   = zlo_n & ~1;
        };
        auto issue = [&]() {
            int gxc = min(max(xlo_n + rx, 0), DVOX - 1);
            int gyc = min(max(ylo_n + ry, 0), DVOX - 1);
            const unsigned* p = (const unsigned*)(V + ((gxc << 12) + (gyc << 6) + s_n));
            uint32x4 q0 = *(const uint32x4*)p;
            uint32x4 q1 = *(const uint32x4*)(p + 4);
            unsigned q2 = p[8];
            d[0] = q0[0]; d[1] = q0[1]; d[2] = q0[2]; d[3] = q0[3];
            d[4] = q1[0]; d[5] = q1[1]; d[6] = q1[2]; d[7] = q1[3];
            d[8] = q2;
        };

        bbox(7); issue();
        int xlo = xlo_n, ylo = ylo_n, zlo = zlo_n, s = s_n;

        float img = 0.f;
#pragma unroll 1
        for (int ch = 7; ch >= 0; --ch) {
            bool zint = (zlo >= 0) && (zlo + 17 <= DVOX);
            {
                bool rv = ((unsigned)(xlo + rx) < (unsigned)DVOX) &
                          ((unsigned)(ylo + ry) < (unsigned)DVOX);
                unsigned tt[9];
#pragma unroll
                for (int k = 0; k < 9; ++k) tt[k] = d[k];
                if (!zint) {
#pragma unroll
                    for (int k = 0; k < 9; ++k) {
                        int h0 = s + 2 * k;
                        unsigned m = (((unsigned)h0 < (unsigned)DVOX) ? 0x0000FFFFu : 0u)
                                   | (((unsigned)(h0 + 1) < (unsigned)DVOX) ? 0xFFFF0000u : 0u);
                        tt[k] &= m;
                    }
                }
                unsigned rvm = rv ? 0xFFFFFFFFu : 0u;
#pragma unroll
                for (int k = 0; k < 9; ++k) tt[k] &= rvm;
                unsigned A[8];
#pragma unroll
                for (int m = 0; m < 8; ++m)
                    A[m] = (tt[m] >> 16) | (tt[m + 1] << 16);
                unsigned* wrow = sV + tid * 17;
                if (zlo & 1) {
#pragma unroll
                    for (int m = 0; m < 8; ++m) {
                        wrow[2 * m]     = A[m];
                        wrow[2 * m + 1] = tt[m + 1];
                    }
                } else {
#pragma unroll
                    for (int m = 0; m < 8; ++m) {
                        wrow[2 * m]     = tt[m];
                        wrow[2 * m + 1] = A[m];
                    }
                }
            }
            __syncthreads();

            if (ch > 0) { bbox(ch - 1); issue(); }

            float T = 1.f, E = 0.f;
            int k0 = ch * 8;
#pragma unroll
            for (int q = 1; q >= 0; --q) {
                int kk = 2 * seg + q;
                float dk = (float)(k0 + kk) - c;
                float x = fmaf(R2, dk, xb);
                float y = fmaf(R5, dk, yb);
                float z = fmaf(R8, dk, zb);
                float xf = floorf(x), yf = floorf(y), zf = floorf(z);
                float fx = x - xf, fy = y - yf, fz = z - zf;
                int xi = (int)xf - xlo;
                int yi = (int)yf - ylo;
                int zi = (int)zf - zlo;
                const unsigned* e = sV + (xi * 272 + yi * 17 + zi);
                float c00 = zlerp(e[0],   fz);
                float c01 = zlerp(e[17],  fz);
                float c10 = zlerp(e[272], fz);
                float c11 = zlerp(e[289], fz);
                float c0 = c00 + (c01 - c00) * fy;
                float c1 = c10 + (c11 - c10) * fy;
                float a  = c0  + (c1  - c0 ) * fx;
                E = E * (1.f - a) + a;
                T *= (1.f - a);
            }
            sT[seg][pix] = T;
            sE[seg][pix] = E;
            __syncthreads();

            if (seg == 0) {
                float im = img;
#pragma unroll
                for (int ss = 3; ss >= 0; --ss)
                    im = fmaf(sT[ss][pix], im, sE[ss][pix]);
                img = im;
            }
            xlo = xlo_n; ylo = ylo_n; zlo = zlo_n; s = s_n;
        }

        if (seg == 0)
            out[b * (DVOX * DVOX) + i * DVOX + j] = 2.f * img - 1.f;
        __syncthreads();                  // fold reads done before next tile's pack
    }
}

// ===================== FALLBACK (non-cooperative R12 trio) =================
__global__ void prep_kernel(const float* __restrict__ enc,
                            const float* __restrict__ angles,
                            unsigned short* __restrict__ encB,
                            float* __restrict__ Rmat) {
    int tid = threadIdx.x;
    for (int idx = tid; idx < BATCH * LAT; idx += blockDim.x) {
        __hip_bfloat16 h = __float2bfloat16(enc[idx]);
        encB[idx] = *reinterpret_cast<unsigned short*>(&h);
    }
    if (tid < BATCH) {
        float ax = angles[tid*3+0], ay = angles[tid*3+1], az = angles[tid*3+2];
        float cx = cosf(ax), sx = sinf(ax);
        float cy = cosf(ay), sy = sinf(ay);
        float cz = cosf(az), sz = sinf(az);
        float* R = Rmat + tid * 9;
        R[0] = cz*cy;  R[1] = cz*sy*sx - sz*cx;  R[2] = cz*sy*cx + sz*sx;
        R[3] = sz*cy;  R[4] = sz*sy*sx + cz*cx;  R[5] = sz*sy*cx - cz*sx;
        R[6] = -sy;    R[7] = cy*sx;             R[8] = cy*cx;
    }
}

__global__ __launch_bounds__(256, 2) void gemm_fb_kernel(
        const unsigned short* __restrict__ encB,
        const float* __restrict__ W,
        const float* __restrict__ bias,
        __half* __restrict__ vox) {
    int wave = threadIdx.x >> 6;
    int lane = threadIdx.x & 63;
    int l15 = lane & 15, l4 = lane >> 4;
    int n4 = blockIdx.x * 256 + wave * 64 + 4 * l15;

    f32x4 acc[4][4];
#pragma unroll
    for (int t = 0; t < 4; ++t)
#pragma unroll
        for (int mt = 0; mt < 4; ++mt) acc[t][mt] = (f32x4){0.f, 0.f, 0.f, 0.f};

    const unsigned short* ap = encB + l15 * LAT + l4 * 8;
    const float* wp = W + (size_t)(l4 * 8) * VOX + n4;
    float4 w0[8], w1[8], w2[8];
    auto loadbuf = [&](float4* buf, int kb) {
        const float* q = wp + (size_t)kb * VOX;
#pragma unroll
        for (int j = 0; j < 8; ++j) buf[j] = *(const float4*)(q + (size_t)j * VOX);
    };
    auto consume = [&](const float4* w, int kb) {
        short8 a[4];
#pragma unroll
        for (int mt = 0; mt < 4; ++mt)
            a[mt] = *(const short8*)(ap + mt * 16 * LAT + kb);
        short8 bf[4];
#pragma unroll
        for (int t = 0; t < 4; ++t) {
            unsigned bw[4];
#pragma unroll
            for (int dw = 0; dw < 4; ++dw) {
                unsigned u0 = __float_as_uint(((const float*)&w[2 * dw])[t])     + 0x8000u;
                unsigned u1 = __float_as_uint(((const float*)&w[2 * dw + 1])[t]) + 0x8000u;
                bw[dw] = __builtin_amdgcn_perm(u1, u0, 0x07060302u);
            }
            bf[t] = *reinterpret_cast<short8*>(bw);
        }
#pragma unroll
        for (int t = 0; t < 4; ++t)
#pragma unroll
            for (int mt = 0; mt < 4; ++mt)
                acc[t][mt] = __builtin_amdgcn_mfma_f32_16x16x32_bf16(a[mt], bf[t], acc[t][mt], 0, 0, 0);
    };
    loadbuf(w0, 0);
    loadbuf(w1, 32);
    loadbuf(w2, 64);  consume(w0, 0);
    loadbuf(w0, 96);  consume(w1, 32);
    loadbuf(w1, 128); consume(w2, 64);
    loadbuf(w2, 160); consume(w0, 96);
    loadbuf(w0, 192); consume(w1, 128);
    loadbuf(w1, 224); consume(w2, 160);
    consume(w0, 192);
    consume(w1, 224);

    float4 bv = *(const float4*)(bias + n4);
#pragma unroll
    for (int mt = 0; mt < 4; ++mt) {
#pragma unroll
        for (int r = 0; r < 4; ++r) {
            int b = mt * 16 + l4 * 4 + r;
            float s[4];
#pragma unroll
            for (int t = 0; t < 4; ++t) {
                float x = acc[t][mt][r] + ((const float*)&bv)[t];
                float v = 1.f / (1.f + __expf(-x));
                v = v * v; v = v * v; v = v * v;
                s[t] = v;
            }
            __half2 h01 = __floats2half2_rn(s[0], s[1]);
            __half2 h23 = __floats2half2_rn(s[2], s[3]);
            uint2 pk;
            pk.x = *reinterpret_cast<unsigned*>(&h01);
            pk.y = *reinterpret_cast<unsigned*>(&h23);
            *reinterpret_cast<uint2*>(vox + (size_t)b * VOX + n4) = pk;
        }
    }
}

__global__ __launch_bounds__(256) void render_fb_kernel(
        const __half* __restrict__ vox,
        const float* __restrict__ Rmat,
        float* __restrict__ out) {
    __shared__ unsigned sV[16 * 16 * 17];
    __shared__ float sT[4][64], sE[4][64];

    int bid  = blockIdx.x;
    int b    = bid & 63;
    int tile = bid >> 6;
    int t    = threadIdx.x;
    int pix  = t & 63, seg = t >> 6;
    int i0 = (tile >> 3) * 8, j0 = (tile & 7) * 8;
    int i = i0 + (pix >> 3);
    int j = j0 + (pix & 7);

    const float* Rb = Rmat + b * 9;
    float R0 = Rb[0], R1 = Rb[1], R2 = Rb[2];
    float R3 = Rb[3], R4 = Rb[4], R5 = Rb[5];
    float R6 = Rb[6], R7 = Rb[7], R8 = Rb[8];

    const float c = (DVOX - 1) * 0.5f;
    float di = (float)i - c, dj = (float)j - c;
    float xb = fmaf(R0, di, fmaf(R1, dj, c));
    float yb = fmaf(R3, di, fmaf(R4, dj, c));
    float zb = fmaf(R6, di, fmaf(R7, dj, c));
    float dic = (float)i0 + 3.5f - c;
    float djc = (float)j0 + 3.5f - c;
    float hwx = 3.5f * (fabsf(R0) + fabsf(R1) + fabsf(R2)) + 1e-3f;
    float hwy = 3.5f * (fabsf(R3) + fabsf(R4) + fabsf(R5)) + 1e-3f;
    float hwz = 3.5f * (fabsf(R6) + fabsf(R7) + fabsf(R8)) + 1e-3f;
    const unsigned short* V = (const unsigned short*)vox + (size_t)b * VOX;

    int rx = t >> 4, ry = t & 15;
    unsigned d[9];
    int xlo_n, ylo_n, zlo_n, s_n;
    auto bbox = [&](int ch) {
        float dkc = (float)(ch * 8) + 3.5f - c;
        float xc = fmaf(R0, dic, fmaf(R1, djc, fmaf(R2, dkc, c)));
        float yc = fmaf(R3, dic, fmaf(R4, djc, fmaf(R5, dkc, c)));
        float zc = fmaf(R6, dic, fmaf(R7, djc, fmaf(R8, dkc, c)));
        xlo_n = (int)floorf(xc - hwx);
        ylo_n = (int)floorf(yc - hwy);
        zlo_n = (int)floorf(zc - hwz);
        s_n   = zlo_n & ~1;
    };
    auto issue = [&]() {
        int gxc = min(max(xlo_n + rx, 0), DVOX - 1);
        int gyc = min(max(ylo_n + ry, 0), DVOX - 1);
        const unsigned* p = (const unsigned*)(V + ((gxc << 12) + (gyc << 6) + s_n));
        uint32x4 q0 = *(const uint32x4*)p;
        uint32x4 q1 = *(const uint32x4*)(p + 4);
        unsigned q2 = p[8];
        d[0] = q0[0]; d[1] = q0[1]; d[2] = q0[2]; d[3] = q0[3];
        d[4] = q1[0]; d[5] = q1[1]; d[6] = q1[2]; d[7] = q1[3];
        d[8] = q2;
    };

    bbox(7); issue();
    int xlo = xlo_n, ylo = ylo_n, zlo = zlo_n, s = s_n;

    float img = 0.f;
#pragma unroll 1
    for (int ch = 7; ch >= 0; --ch) {
        bool zint = (zlo >= 0) && (zlo + 17 <= DVOX);
        {
            bool rv = ((unsigned)(xlo + rx) < (unsigned)DVOX) &
                      ((unsigned)(ylo + ry) < (unsigned)DVOX);
            unsigned tt[9];
#pragma unroll
            for (int k = 0; k < 9; ++k) tt[k] = d[k];
            if (!zint) {
#pragma unroll
                for (int k = 0; k < 9; ++k) {
                    int h0 = s + 2 * k;
                    unsigned m = (((unsigned)h0 < (unsigned)DVOX) ? 0x0000FFFFu : 0u)
                               | (((unsigned)(h0 + 1) < (unsigned)DVOX) ? 0xFFFF0000u : 0u);
                    tt[k] &= m;
                }
            }
            unsigned rvm = rv ? 0xFFFFFFFFu : 0u;
#pragma unroll
            for (int k = 0; k < 9; ++k) tt[k] &= rvm;
            unsigned A[8];
#pragma unroll
            for (int m = 0; m < 8; ++m)
                A[m] = (tt[m] >> 16) | (tt[m + 1] << 16);
            unsigned* wrow = sV + t * 17;
            if (zlo & 1) {
#pragma unroll
                for (int m = 0; m < 8; ++m) { wrow[2*m] = A[m]; wrow[2*m+1] = tt[m+1]; }
            } else {
#pragma unroll
                for (int m = 0; m < 8; ++m) { wrow[2*m] = tt[m]; wrow[2*m+1] = A[m]; }
            }
        }
        __syncthreads();
        if (ch > 0) { bbox(ch - 1); issue(); }

        float T = 1.f, E = 0.f;
        int k0 = ch * 8;
#pragma unroll
        for (int q = 1; q >= 0; --q) {
            int kk = 2 * seg + q;
            float dk = (float)(k0 + kk) - c;
            float x = fmaf(R2, dk, xb);
            float y = fmaf(R5, dk, yb);
            float z = fmaf(R8, dk, zb);
            float xf = floorf(x), yf = floorf(y), zf = floorf(z);
            float fx = x - xf, fy = y - yf, fz = z - zf;
            int xi = (int)xf - xlo;
            int yi = (int)yf - ylo;
            int zi = (int)zf - zlo;
            const unsigned* e = sV + (xi * 272 + yi * 17 + zi);
            float c00 = zlerp(e[0],   fz);
            float c01 = zlerp(e[17],  fz);
            float c10 = zlerp(e[272], fz);
            float c11 = zlerp(e[289], fz);
            float c0 = c00 + (c01 - c00) * fy;
            float c1 = c10 + (c11 - c10) * fy;
            float a  = c0  + (c1  - c0 ) * fx;
            E = E * (1.f - a) + a;
            T *= (1.f - a);
        }
        sT[seg][pix] = T;
        sE[seg][pix] = E;
        __syncthreads();
        if (seg == 0) {
            float im = img;
#pragma unroll
            for (int ss = 3; ss >= 0; --ss)
                im = fmaf(sT[ss][pix], im, sE[ss][pix]);
            img = im;
        }
        xlo = xlo_n; ylo = ylo_n; zlo = zlo_n; s = s_n;
    }

    if (seg == 0)
        out[b * (DVOX * DVOX) + i * DVOX + j] = 2.f * img - 1.f;
}

// ---------------------------------------------------------------------------
extern "C" void kernel_launch(void* const* d_in, const int* in_sizes, int n_in,
                              void* d_out, int out_size, void* d_ws, size_t ws_size,
                              hipStream_t stream) {
    const float* enc    = (const float*)d_in[0];
    const float* W      = (const float*)d_in[1];
    const float* bias   = (const float*)d_in[2];
    const float* angles = (const float*)d_in[3];
    float* out = (float*)d_out;

    char* ws = (char*)d_ws;
    unsigned short* encB = (unsigned short*)ws;           // 32 KB (fallback)
    float* Rmat          = (float*)(ws + 32768);          // (fallback)
    __half* vox          = (__half*)(ws + 65536);         // 32 MiB

    void* args[] = {(void*)&enc, (void*)&W, (void*)&bias,
                    (void*)&angles, (void*)&vox, (void*)&out};
    hipError_t err = hipLaunchCooperativeKernel(
        (const void*)fused_kernel, dim3(512), dim3(256), args, 0, stream);
    if (err != hipSuccess) {
        // graceful fallback: R12 trio (non-cooperative)
        prep_kernel<<<1, 256, 0, stream>>>(enc, angles, encB, Rmat);
        gemm_fb_kernel<<<VOX / 256, 256, 0, stream>>>(encB, W, bias, vox);
        render_fb_kernel<<<BATCH * 64, 256, 0, stream>>>(vox, Rmat, out);
    }
}

// Round 19
// 138.591 us; speedup vs baseline: 1.4565x; 1.4565x over previous
//
#include <hip/hip_runtime.h>
#include <hip/hip_bf16.h>
#include <hip/hip_fp16.h>
#include <math.h>

#define BATCH 64
#define LAT   256
#define DVOX  64
#define VOX   (DVOX*DVOX*DVOX)   // 262144

typedef __attribute__((ext_vector_type(8))) short short8;
typedef __attribute__((ext_vector_type(4))) float f32x4;
typedef unsigned uint32x4 __attribute__((ext_vector_type(4), aligned(4)));

// ---------------- kernel 0: enc -> bf16, build rotation matrices -----------
__global__ void prep_kernel(const float* __restrict__ enc,      // [64,256]
                            const float* __restrict__ angles,   // [64,3]
                            unsigned short* __restrict__ encB,  // [64,256] bf16 bits
                            float* __restrict__ Rmat) {         // [64,9]
    int tid = threadIdx.x;
    for (int idx = tid; idx < BATCH * LAT; idx += blockDim.x) {
        __hip_bfloat16 h = __float2bfloat16(enc[idx]);
        encB[idx] = *reinterpret_cast<unsigned short*>(&h);
    }
    if (tid < BATCH) {
        float ax = angles[tid*3+0], ay = angles[tid*3+1], az = angles[tid*3+2];
        float cx = cosf(ax), sx = sinf(ax);
        float cy = cosf(ay), sy = sinf(ay);
        float cz = cosf(az), sz = sinf(az);
        float* R = Rmat + tid * 9;
        R[0] = cz*cy;  R[1] = cz*sy*sx - sz*cx;  R[2] = cz*sy*cx + sz*sx;
        R[3] = sz*cy;  R[4] = sz*sy*sx + cz*cx;  R[5] = sz*sy*cx - cz*sx;
        R[6] = -sy;    R[7] = cy*sx;             R[8] = cy*cx;
    }
}

// ---------------- kernel 1: counted-vmcnt double-buffer LDS GEMM -----------
// The one untested combination: TRUE overlap (counted vmcnt, never drain-0
// in the loop) AND 2 blocks/CU (67 KB LDS). Per K-step: issue {A,W}(kt+1)
// -> vmcnt(12) (tile kt retired; kt+1's 12 VMEM stay in flight ACROSS the
// barrier) -> s_barrier -> compute(kt) -> s_barrier. R14 drained via
// __syncthreads (0 overlap); R17 overlapped but at 1 block/CU.
#define LROW 260                         // dwords/row (256 + pad; +rotate<=24)
#define LBUF 8352                        // max write 8340 < 8352

__device__ __forceinline__ void gload_lds16(const float* g, unsigned* l) {
    __builtin_amdgcn_global_load_lds(
        (__attribute__((address_space(1))) void*)(g),
        (__attribute__((address_space(3))) void*)(l),
        16, 0, 0);
}

__global__ __launch_bounds__(256) void gemm_mfma_kernel(
        const unsigned short* __restrict__ encB,  // [64,256] bf16
        const float* __restrict__ W,              // [256, 262144]
        const float* __restrict__ bias,           // [262144]
        __half* __restrict__ vox) {               // [64, 262144] fp16
    __shared__ unsigned lds[2 * LBUF];            // 66,816 B -> 2 blocks/CU

    int wave = threadIdx.x >> 6;
    int lane = threadIdx.x & 63;
    int l15 = lane & 15, l4 = lane >> 4;
    int n0 = blockIdx.x * 256;
    int n4 = n0 + wave * 64 + 4 * l15;

    const unsigned short* ap = encB + l15 * LAT + l4 * 8;
    const float* gb = W + n0 + lane * 4;

    f32x4 acc[4][4];
#pragma unroll
    for (int t = 0; t < 4; ++t)
#pragma unroll
        for (int mt = 0; mt < 4; ++mt) acc[t][mt] = (f32x4){0.f, 0.f, 0.f, 0.f};

    short8 a[2][4];                               // 2-slot A rotation

    auto loadA = [&](short8* as, int kb) {
#pragma unroll
        for (int mt = 0; mt < 4; ++mt)
            as[mt] = *(const short8*)(ap + mt * 16 * LAT + kb);   // 4 VMEM
    };
    auto stageW = [&](int buf, int kb) {
        unsigned* lb = lds + buf * LBUF;
#pragma unroll
        for (int i = 0; i < 8; ++i) {             // 8 VMEM (1 KB rows)
            int row = i * 4 + wave;
            gload_lds16(gb + (size_t)(kb + row) * VOX,
                        lb + row * LROW + ((row >> 3) & 3) * 8);
        }
    };
    auto compute = [&](int buf, const short8* as) {
        const unsigned* lb = lds + buf * LBUF
                           + (l4 * 8) * LROW + l4 * 8
                           + wave * 64 + 4 * l15;
        uint4 dj[8];
#pragma unroll
        for (int j = 0; j < 8; ++j)
            dj[j] = *(const uint4*)(lb + j * LROW);
        short8 bf[4];
#pragma unroll
        for (int t = 0; t < 4; ++t) {
            unsigned bw[4];
#pragma unroll
            for (int dw = 0; dw < 4; ++dw) {
                unsigned u0 = ((const unsigned*)&dj[2 * dw])[t]     + 0x8000u;
                unsigned u1 = ((const unsigned*)&dj[2 * dw + 1])[t] + 0x8000u;
                bw[dw] = __builtin_amdgcn_perm(u1, u0, 0x07060302u);
            }
            bf[t] = *reinterpret_cast<short8*>(bw);
        }
#pragma unroll
        for (int t = 0; t < 4; ++t)
#pragma unroll
            for (int mt = 0; mt < 4; ++mt)
                acc[t][mt] = __builtin_amdgcn_mfma_f32_16x16x32_bf16(as[mt], bf[t], acc[t][mt], 0, 0, 0);
    };

    // prologue: tile 0 in flight
    loadA(a[0], 0);  stageW(0, 0);

#define KSTEP(kt, WAITSTR)                                        \
    {                                                             \
        if ((kt) + 1 < 8) {                                       \
            loadA(a[((kt) + 1) & 1], ((kt) + 1) * 32);            \
            stageW(((kt) + 1) & 1, ((kt) + 1) * 32);              \
        }                                                         \
        asm volatile(WAITSTR ::: "memory");                       \
        __builtin_amdgcn_sched_barrier(0);                        \
        __builtin_amdgcn_s_barrier();                             \
        __builtin_amdgcn_sched_barrier(0);                        \
        compute((kt) & 1, a[(kt) & 1]);                           \
        __builtin_amdgcn_s_barrier();                             \
    }

    KSTEP(0, "s_waitcnt vmcnt(12)")
    KSTEP(1, "s_waitcnt vmcnt(12)")
    KSTEP(2, "s_waitcnt vmcnt(12)")
    KSTEP(3, "s_waitcnt vmcnt(12)")
    KSTEP(4, "s_waitcnt vmcnt(12)")
    KSTEP(5, "s_waitcnt vmcnt(12)")
    KSTEP(6, "s_waitcnt vmcnt(12)")
    KSTEP(7, "s_waitcnt vmcnt(0)")
#undef KSTEP

    float4 bv = *(const float4*)(bias + n4);
#pragma unroll
    for (int mt = 0; mt < 4; ++mt) {
#pragma unroll
        for (int r = 0; r < 4; ++r) {
            int b = mt * 16 + l4 * 4 + r;
            float s[4];
#pragma unroll
            for (int t = 0; t < 4; ++t) {
                float x = acc[t][mt][r] + ((const float*)&bv)[t];
                float v = 1.f / (1.f + __expf(-x));   // sigmoid
                v = v * v; v = v * v; v = v * v;      // ^8
                s[t] = v;
            }
            __half2 h01 = __floats2half2_rn(s[0], s[1]);
            __half2 h23 = __floats2half2_rn(s[2], s[3]);
            uint2 pk;
            pk.x = *reinterpret_cast<unsigned*>(&h01);
            pk.y = *reinterpret_cast<unsigned*>(&h23);
            *reinterpret_cast<uint2*>(vox + (size_t)b * VOX + n4) = pk;
        }
    }
}

// ---------------- kernel 2: 4-wave cooperative LDS-brick resample ----------
// (exact round-12 build)
__device__ __forceinline__ float zlerp(unsigned e, float fz) {
    __half2 h = *reinterpret_cast<__half2*>(&e);
    float2 f = __half22float2(h);
    return f.x + (f.y - f.x) * fz;
}

__global__ __launch_bounds__(256) void render_lds_kernel(
        const __half* __restrict__ vox,   // [64, 262144] fp16
        const float* __restrict__ Rmat,   // [64,9]
        float* __restrict__ out) {        // [64,1,64,64]
    __shared__ unsigned sV[16 * 16 * 17]; // 17408 B brick, row stride 17
    __shared__ float sT[4][64], sE[4][64];

    int bid  = blockIdx.x;
    int b    = bid & 63;                  // bid%8 == b%8 -> XCD affinity
    int tile = bid >> 6;
    int t    = threadIdx.x;
    int pix  = t & 63, seg = t >> 6;      // seg == wave id
    int i0 = (tile >> 3) * 8, j0 = (tile & 7) * 8;
    int i = i0 + (pix >> 3);
    int j = j0 + (pix & 7);

    const float* Rb = Rmat + b * 9;       // uniform -> scalar loads
    float R0 = Rb[0], R1 = Rb[1], R2 = Rb[2];
    float R3 = Rb[3], R4 = Rb[4], R5 = Rb[5];
    float R6 = Rb[6], R7 = Rb[7], R8 = Rb[8];

    const float c = (DVOX - 1) * 0.5f;    // 31.5
    float di = (float)i - c, dj = (float)j - c;
    float xb = fmaf(R0, di, fmaf(R1, dj, c));
    float yb = fmaf(R3, di, fmaf(R4, dj, c));
    float zb = fmaf(R6, di, fmaf(R7, dj, c));

    float dic = (float)i0 + 3.5f - c;     // tile-center offsets (uniform)
    float djc = (float)j0 + 3.5f - c;
    float hwx = 3.5f * (fabsf(R0) + fabsf(R1) + fabsf(R2)) + 1e-3f;
    float hwy = 3.5f * (fabsf(R3) + fabsf(R4) + fabsf(R5)) + 1e-3f;
    float hwz = 3.5f * (fabsf(R6) + fabsf(R7) + fabsf(R8)) + 1e-3f;

    const unsigned short* V = (const unsigned short*)vox + (size_t)b * VOX;

    // this thread's staging row: x = t>>4, y = t&15
    int rx = t >> 4, ry = t & 15;
    unsigned d[9];
    int xlo_n, ylo_n, zlo_n, s_n;

    auto bbox = [&](int ch) {
        float dkc = (float)(ch * 8) + 3.5f - c;
        float xc = fmaf(R0, dic, fmaf(R1, djc, fmaf(R2, dkc, c)));
        float yc = fmaf(R3, dic, fmaf(R4, djc, fmaf(R5, dkc, c)));
        float zc = fmaf(R6, dic, fmaf(R7, djc, fmaf(R8, dkc, c)));
        xlo_n = (int)floorf(xc - hwx);
        ylo_n = (int)floorf(yc - hwy);
        zlo_n = (int)floorf(zc - hwz);
        s_n   = zlo_n & ~1;
    };
    auto issue = [&]() {
        int gxc = min(max(xlo_n + rx, 0), DVOX - 1);
        int gyc = min(max(ylo_n + ry, 0), DVOX - 1);
        const unsigned* p = (const unsigned*)(V + ((gxc << 12) + (gyc << 6) + s_n));
        uint32x4 q0 = *(const uint32x4*)p;        // dwordx4 (4B-align ok)
        uint32x4 q1 = *(const uint32x4*)(p + 4);
        unsigned q2 = p[8];
        d[0] = q0[0]; d[1] = q0[1]; d[2] = q0[2]; d[3] = q0[3];
        d[4] = q1[0]; d[5] = q1[1]; d[6] = q1[2]; d[7] = q1[3];
        d[8] = q2;
    };

    bbox(7); issue();
    int xlo = xlo_n, ylo = ylo_n, zlo = zlo_n, s = s_n;

    float img = 0.f;                      // live in wave 0 only
#pragma unroll 1
    for (int ch = 7; ch >= 0; --ch) {     // back-to-front chunks of 8 z
        bool zint = (zlo >= 0) && (zlo + 17 <= DVOX);

        // ---- pack this thread's row into the brick ------------------------
        {
            bool rv = ((unsigned)(xlo + rx) < (unsigned)DVOX) &
                      ((unsigned)(ylo + ry) < (unsigned)DVOX);
            unsigned tt[9];
#pragma unroll
            for (int k = 0; k < 9; ++k) tt[k] = d[k];
            if (!zint) {                  // block-uniform branch
#pragma unroll
                for (int k = 0; k < 9; ++k) {
                    int h0 = s + 2 * k;
                    unsigned m = (((unsigned)h0 < (unsigned)DVOX) ? 0x0000FFFFu : 0u)
                               | (((unsigned)(h0 + 1) < (unsigned)DVOX) ? 0xFFFF0000u : 0u);
                    tt[k] &= m;
                }
            }
            unsigned rvm = rv ? 0xFFFFFFFFu : 0u;
#pragma unroll
            for (int k = 0; k < 9; ++k) tt[k] &= rvm;

            unsigned A[8];
#pragma unroll
            for (int m = 0; m < 8; ++m)
                A[m] = (tt[m] >> 16) | (tt[m + 1] << 16);   // v_alignbit

            unsigned* wrow = sV + t * 17;
            if (zlo & 1) {                // block-uniform
#pragma unroll
                for (int m = 0; m < 8; ++m) {
                    wrow[2 * m]     = A[m];
                    wrow[2 * m + 1] = tt[m + 1];
                }
            } else {
#pragma unroll
                for (int m = 0; m < 8; ++m) {
                    wrow[2 * m]     = tt[m];
                    wrow[2 * m + 1] = A[m];
                }
            }
        }
        __syncthreads();

        // ---- issue NEXT chunk's loads (latency hides under sampling) ------
        if (ch > 0) { bbox(ch - 1); issue(); }

        // ---- sample this wave's 2-z segment, back-to-front ----------------
        float T = 1.f, E = 0.f;
        int k0 = ch * 8;
#pragma unroll
        for (int q = 1; q >= 0; --q) {    // kk = 2*seg+1, then 2*seg
            int kk = 2 * seg + q;
            float dk = (float)(k0 + kk) - c;
            float x = fmaf(R2, dk, xb);
            float y = fmaf(R5, dk, yb);
            float z = fmaf(R8, dk, zb);

            float xf = floorf(x), yf = floorf(y), zf = floorf(z);
            float fx = x - xf, fy = y - yf, fz = z - zf;
            int xi = (int)xf - xlo;       // [0,14]
            int yi = (int)yf - ylo;
            int zi = (int)zf - zlo;
            const unsigned* e = sV + (xi * 272 + yi * 17 + zi);

            float c00 = zlerp(e[0],   fz);   // (x0,y0)
            float c01 = zlerp(e[17],  fz);   // (x0,y1)
            float c10 = zlerp(e[272], fz);   // (x1,y0)
            float c11 = zlerp(e[289], fz);   // (x1,y1)
            float c0 = c00 + (c01 - c00) * fy;
            float c1 = c10 + (c11 - c10) * fy;
            float a  = c0  + (c1  - c0 ) * fx;

            E = E * (1.f - a) + a;
            T *= (1.f - a);
        }
        sT[seg][pix] = T;
        sE[seg][pix] = E;
        __syncthreads();

        // ---- wave 0 folds the 4 segments (back seg 3 first) ---------------
        if (seg == 0) {
            float im = img;
#pragma unroll
            for (int ss = 3; ss >= 0; --ss)
                im = fmaf(sT[ss][pix], im, sE[ss][pix]);
            img = im;
        }
        // next chunk's sT/sE writes are ordered after this fold by the
        // pack-side __syncthreads() of the next iteration.

        xlo = xlo_n; ylo = ylo_n; zlo = zlo_n; s = s_n;
    }

    if (seg == 0)
        out[b * (DVOX * DVOX) + i * DVOX + j] = 2.f * img - 1.f;
}

// ---------------------------------------------------------------------------
extern "C" void kernel_launch(void* const* d_in, const int* in_sizes, int n_in,
                              void* d_out, int out_size, void* d_ws, size_t ws_size,
                              hipStream_t stream) {
    const float* enc    = (const float*)d_in[0];
    const float* W      = (const float*)d_in[1];
    const float* bias   = (const float*)d_in[2];
    const float* angles = (const float*)d_in[3];
    float* out = (float*)d_out;

    char* ws = (char*)d_ws;
    unsigned short* encB = (unsigned short*)ws;           // 32 KB
    float* Rmat          = (float*)(ws + 32768);          // 2.3 KB
    __half* vox          = (__half*)(ws + 65536);         // 32 MiB

    prep_kernel<<<1, 256, 0, stream>>>(enc, angles, encB, Rmat);
    gemm_mfma_kernel<<<VOX / 256, 256, 0, stream>>>(encB, W, bias, vox);
    render_lds_kernel<<<BATCH * 64, 256, 0, stream>>>(vox, Rmat, out);
}

// Round 20
// 132.220 us; speedup vs baseline: 1.5267x; 1.0482x over previous
//
#include <hip/hip_runtime.h>
#include <hip/hip_bf16.h>
#include <hip/hip_fp16.h>
#include <math.h>

#define BATCH 64
#define LAT   256
#define DVOX  64
#define VOX   (DVOX*DVOX*DVOX)   // 262144

typedef __attribute__((ext_vector_type(8))) short short8;
typedef __attribute__((ext_vector_type(4))) float f32x4;
typedef unsigned uint32x4 __attribute__((ext_vector_type(4), aligned(4)));

// ---------------- kernel 0: enc -> bf16, build rotation matrices -----------
__global__ void prep_kernel(const float* __restrict__ enc,      // [64,256]
                            const float* __restrict__ angles,   // [64,3]
                            unsigned short* __restrict__ encB,  // [64,256] bf16 bits
                            float* __restrict__ Rmat) {         // [64,9]
    int tid = threadIdx.x;
    for (int idx = tid; idx < BATCH * LAT; idx += blockDim.x) {
        __hip_bfloat16 h = __float2bfloat16(enc[idx]);
        encB[idx] = *reinterpret_cast<unsigned short*>(&h);
    }
    if (tid < BATCH) {
        float ax = angles[tid*3+0], ay = angles[tid*3+1], az = angles[tid*3+2];
        float cx = cosf(ax), sx = sinf(ax);
        float cy = cosf(ay), sy = sinf(ay);
        float cz = cosf(az), sz = sinf(az);
        float* R = Rmat + tid * 9;
        R[0] = cz*cy;  R[1] = cz*sy*sx - sz*cx;  R[2] = cz*sy*cx + sz*sx;
        R[3] = sz*cy;  R[4] = sz*sy*sx + cz*cx;  R[5] = sz*sy*cx - cz*sx;
        R[6] = -sy;    R[7] = cy*sx;             R[8] = cy*cx;
    }
}

// ---------------- kernel 1: counted-vmcnt dbuf GEMM + NT W-stream ----------
// R19 structure (counted vmcnt, 2 blocks/CU) + ONE change: the W staging
// loads carry aux=2 (CPol NT, non-temporal). W is read-once-per-launch and
// 268 MB > 256 MB LLC: default policy inserts every line into L2+L3 and
// thrashes (R13: FETCH 100 MB/268 -> L3 half-serves the replayed stream at
// ~3.4 TB/s). NT skips allocation -> stream at HBM rate. Semantics unchanged.
#define LROW 260                         // dwords/row (256 + pad; +rotate<=24)
#define LBUF 8352                        // max write 8340 < 8352

__device__ __forceinline__ void gload_lds16_nt(const float* g, unsigned* l) {
    __builtin_amdgcn_global_load_lds(
        (__attribute__((address_space(1))) void*)(g),
        (__attribute__((address_space(3))) void*)(l),
        16, 0, 2);                        // aux=2: NT (non-temporal)
}

__global__ __launch_bounds__(256) void gemm_mfma_kernel(
        const unsigned short* __restrict__ encB,  // [64,256] bf16
        const float* __restrict__ W,              // [256, 262144]
        const float* __restrict__ bias,           // [262144]
        __half* __restrict__ vox) {               // [64, 262144] fp16
    __shared__ unsigned lds[2 * LBUF];            // 66,816 B -> 2 blocks/CU

    int wave = threadIdx.x >> 6;
    int lane = threadIdx.x & 63;
    int l15 = lane & 15, l4 = lane >> 4;
    int n0 = blockIdx.x * 256;
    int n4 = n0 + wave * 64 + 4 * l15;

    const unsigned short* ap = encB + l15 * LAT + l4 * 8;
    const float* gb = W + n0 + lane * 4;

    f32x4 acc[4][4];
#pragma unroll
    for (int t = 0; t < 4; ++t)
#pragma unroll
        for (int mt = 0; mt < 4; ++mt) acc[t][mt] = (f32x4){0.f, 0.f, 0.f, 0.f};

    short8 a[2][4];                               // 2-slot A rotation

    auto loadA = [&](short8* as, int kb) {
#pragma unroll
        for (int mt = 0; mt < 4; ++mt)
            as[mt] = *(const short8*)(ap + mt * 16 * LAT + kb);   // 4 VMEM
    };
    auto stageW = [&](int buf, int kb) {
        unsigned* lb = lds + buf * LBUF;
#pragma unroll
        for (int i = 0; i < 8; ++i) {             // 8 VMEM (1 KB rows), NT
            int row = i * 4 + wave;
            gload_lds16_nt(gb + (size_t)(kb + row) * VOX,
                           lb + row * LROW + ((row >> 3) & 3) * 8);
        }
    };
    auto compute = [&](int buf, const short8* as) {
        const unsigned* lb = lds + buf * LBUF
                           + (l4 * 8) * LROW + l4 * 8
                           + wave * 64 + 4 * l15;
        uint4 dj[8];
#pragma unroll
        for (int j = 0; j < 8; ++j)
            dj[j] = *(const uint4*)(lb + j * LROW);
        short8 bf[4];
#pragma unroll
        for (int t = 0; t < 4; ++t) {
            unsigned bw[4];
#pragma unroll
            for (int dw = 0; dw < 4; ++dw) {
                unsigned u0 = ((const unsigned*)&dj[2 * dw])[t]     + 0x8000u;
                unsigned u1 = ((const unsigned*)&dj[2 * dw + 1])[t] + 0x8000u;
                bw[dw] = __builtin_amdgcn_perm(u1, u0, 0x07060302u);
            }
            bf[t] = *reinterpret_cast<short8*>(bw);
        }
#pragma unroll
        for (int t = 0; t < 4; ++t)
#pragma unroll
            for (int mt = 0; mt < 4; ++mt)
                acc[t][mt] = __builtin_amdgcn_mfma_f32_16x16x32_bf16(as[mt], bf[t], acc[t][mt], 0, 0, 0);
    };

    // prologue: tile 0 in flight
    loadA(a[0], 0);  stageW(0, 0);

#define KSTEP(kt, WAITSTR)                                        \
    {                                                             \
        if ((kt) + 1 < 8) {                                       \
            loadA(a[((kt) + 1) & 1], ((kt) + 1) * 32);            \
            stageW(((kt) + 1) & 1, ((kt) + 1) * 32);              \
        }                                                         \
        asm volatile(WAITSTR ::: "memory");                       \
        __builtin_amdgcn_sched_barrier(0);                        \
        __builtin_amdgcn_s_barrier();                             \
        __builtin_amdgcn_sched_barrier(0);                        \
        compute((kt) & 1, a[(kt) & 1]);                           \
        __builtin_amdgcn_s_barrier();                             \
    }

    KSTEP(0, "s_waitcnt vmcnt(12)")
    KSTEP(1, "s_waitcnt vmcnt(12)")
    KSTEP(2, "s_waitcnt vmcnt(12)")
    KSTEP(3, "s_waitcnt vmcnt(12)")
    KSTEP(4, "s_waitcnt vmcnt(12)")
    KSTEP(5, "s_waitcnt vmcnt(12)")
    KSTEP(6, "s_waitcnt vmcnt(12)")
    KSTEP(7, "s_waitcnt vmcnt(0)")
#undef KSTEP

    float4 bv = *(const float4*)(bias + n4);
#pragma unroll
    for (int mt = 0; mt < 4; ++mt) {
#pragma unroll
        for (int r = 0; r < 4; ++r) {
            int b = mt * 16 + l4 * 4 + r;
            float s[4];
#pragma unroll
            for (int t = 0; t < 4; ++t) {
                float x = acc[t][mt][r] + ((const float*)&bv)[t];
                float v = 1.f / (1.f + __expf(-x));   // sigmoid
                v = v * v; v = v * v; v = v * v;      // ^8
                s[t] = v;
            }
            __half2 h01 = __floats2half2_rn(s[0], s[1]);
            __half2 h23 = __floats2half2_rn(s[2], s[3]);
            uint2 pk;
            pk.x = *reinterpret_cast<unsigned*>(&h01);
            pk.y = *reinterpret_cast<unsigned*>(&h23);
            *reinterpret_cast<uint2*>(vox + (size_t)b * VOX + n4) = pk;
        }
    }
}

// ---------------- kernel 2: 4-wave cooperative LDS-brick resample ----------
// (exact round-12 build)
__device__ __forceinline__ float zlerp(unsigned e, float fz) {
    __half2 h = *reinterpret_cast<__half2*>(&e);
    float2 f = __half22float2(h);
    return f.x + (f.y - f.x) * fz;
}

__global__ __launch_bounds__(256) void render_lds_kernel(
        const __half* __restrict__ vox,   // [64, 262144] fp16
        const float* __restrict__ Rmat,   // [64,9]
        float* __restrict__ out) {        // [64,1,64,64]
    __shared__ unsigned sV[16 * 16 * 17]; // 17408 B brick, row stride 17
    __shared__ float sT[4][64], sE[4][64];

    int bid  = blockIdx.x;
    int b    = bid & 63;                  // bid%8 == b%8 -> XCD affinity
    int tile = bid >> 6;
    int t    = threadIdx.x;
    int pix  = t & 63, seg = t >> 6;      // seg == wave id
    int i0 = (tile >> 3) * 8, j0 = (tile & 7) * 8;
    int i = i0 + (pix >> 3);
    int j = j0 + (pix & 7);

    const float* Rb = Rmat + b * 9;       // uniform -> scalar loads
    float R0 = Rb[0], R1 = Rb[1], R2 = Rb[2];
    float R3 = Rb[3], R4 = Rb[4], R5 = Rb[5];
    float R6 = Rb[6], R7 = Rb[7], R8 = Rb[8];

    const float c = (DVOX - 1) * 0.5f;    // 31.5
    float di = (float)i - c, dj = (float)j - c;
    float xb = fmaf(R0, di, fmaf(R1, dj, c));
    float yb = fmaf(R3, di, fmaf(R4, dj, c));
    float zb = fmaf(R6, di, fmaf(R7, dj, c));

    float dic = (float)i0 + 3.5f - c;     // tile-center offsets (uniform)
    float djc = (float)j0 + 3.5f - c;
    float hwx = 3.5f * (fabsf(R0) + fabsf(R1) + fabsf(R2)) + 1e-3f;
    float hwy = 3.5f * (fabsf(R3) + fabsf(R4) + fabsf(R5)) + 1e-3f;
    float hwz = 3.5f * (fabsf(R6) + fabsf(R7) + fabsf(R8)) + 1e-3f;

    const unsigned short* V = (const unsigned short*)vox + (size_t)b * VOX;

    // this thread's staging row: x = t>>4, y = t&15
    int rx = t >> 4, ry = t & 15;
    unsigned d[9];
    int xlo_n, ylo_n, zlo_n, s_n;

    auto bbox = [&](int ch) {
        float dkc = (float)(ch * 8) + 3.5f - c;
        float xc = fmaf(R0, dic, fmaf(R1, djc, fmaf(R2, dkc, c)));
        float yc = fmaf(R3, dic, fmaf(R4, djc, fmaf(R5, dkc, c)));
        float zc = fmaf(R6, dic, fmaf(R7, djc, fmaf(R8, dkc, c)));
        xlo_n = (int)floorf(xc - hwx);
        ylo_n = (int)floorf(yc - hwy);
        zlo_n = (int)floorf(zc - hwz);
        s_n   = zlo_n & ~1;
    };
    auto issue = [&]() {
        int gxc = min(max(xlo_n + rx, 0), DVOX - 1);
        int gyc = min(max(ylo_n + ry, 0), DVOX - 1);
        const unsigned* p = (const unsigned*)(V + ((gxc << 12) + (gyc << 6) + s_n));
        uint32x4 q0 = *(const uint32x4*)p;        // dwordx4 (4B-align ok)
        uint32x4 q1 = *(const uint32x4*)(p + 4);
        unsigned q2 = p[8];
        d[0] = q0[0]; d[1] = q0[1]; d[2] = q0[2]; d[3] = q0[3];
        d[4] = q1[0]; d[5] = q1[1]; d[6] = q1[2]; d[7] = q1[3];
        d[8] = q2;
    };

    bbox(7); issue();
    int xlo = xlo_n, ylo = ylo_n, zlo = zlo_n, s = s_n;

    float img = 0.f;                      // live in wave 0 only
#pragma unroll 1
    for (int ch = 7; ch >= 0; --ch) {     // back-to-front chunks of 8 z
        bool zint = (zlo >= 0) && (zlo + 17 <= DVOX);

        // ---- pack this thread's row into the brick ------------------------
        {
            bool rv = ((unsigned)(xlo + rx) < (unsigned)DVOX) &
                      ((unsigned)(ylo + ry) < (unsigned)DVOX);
            unsigned tt[9];
#pragma unroll
            for (int k = 0; k < 9; ++k) tt[k] = d[k];
            if (!zint) {                  // block-uniform branch
#pragma unroll
                for (int k = 0; k < 9; ++k) {
                    int h0 = s + 2 * k;
                    unsigned m = (((unsigned)h0 < (unsigned)DVOX) ? 0x0000FFFFu : 0u)
                               | (((unsigned)(h0 + 1) < (unsigned)DVOX) ? 0xFFFF0000u : 0u);
                    tt[k] &= m;
                }
            }
            unsigned rvm = rv ? 0xFFFFFFFFu : 0u;
#pragma unroll
            for (int k = 0; k < 9; ++k) tt[k] &= rvm;

            unsigned A[8];
#pragma unroll
            for (int m = 0; m < 8; ++m)
                A[m] = (tt[m] >> 16) | (tt[m + 1] << 16);   // v_alignbit

            unsigned* wrow = sV + t * 17;
            if (zlo & 1) {                // block-uniform
#pragma unroll
                for (int m = 0; m < 8; ++m) {
                    wrow[2 * m]     = A[m];
                    wrow[2 * m + 1] = tt[m + 1];
                }
            } else {
#pragma unroll
                for (int m = 0; m < 8; ++m) {
                    wrow[2 * m]     = tt[m];
                    wrow[2 * m + 1] = A[m];
                }
            }
        }
        __syncthreads();

        // ---- issue NEXT chunk's loads (latency hides under sampling) ------
        if (ch > 0) { bbox(ch - 1); issue(); }

        // ---- sample this wave's 2-z segment, back-to-front ----------------
        float T = 1.f, E = 0.f;
        int k0 = ch * 8;
#pragma unroll
        for (int q = 1; q >= 0; --q) {    // kk = 2*seg+1, then 2*seg
            int kk = 2 * seg + q;
            float dk = (float)(k0 + kk) - c;
            float x = fmaf(R2, dk, xb);
            float y = fmaf(R5, dk, yb);
            float z = fmaf(R8, dk, zb);

            float xf = floorf(x), yf = floorf(y), zf = floorf(z);
            float fx = x - xf, fy = y - yf, fz = z - zf;
            int xi = (int)xf - xlo;       // [0,14]
            int yi = (int)yf - ylo;
            int zi = (int)zf - zlo;
            const unsigned* e = sV + (xi * 272 + yi * 17 + zi);

            float c00 = zlerp(e[0],   fz);   // (x0,y0)
            float c01 = zlerp(e[17],  fz);   // (x0,y1)
            float c10 = zlerp(e[272], fz);   // (x1,y0)
            float c11 = zlerp(e[289], fz);   // (x1,y1)
            float c0 = c00 + (c01 - c00) * fy;
            float c1 = c10 + (c11 - c10) * fy;
            float a  = c0  + (c1  - c0 ) * fx;

            E = E * (1.f - a) + a;
            T *= (1.f - a);
        }
        sT[seg][pix] = T;
        sE[seg][pix] = E;
        __syncthreads();

        // ---- wave 0 folds the 4 segments (back seg 3 first) ---------------
        if (seg == 0) {
            float im = img;
#pragma unroll
            for (int ss = 3; ss >= 0; --ss)
                im = fmaf(sT[ss][pix], im, sE[ss][pix]);
            img = im;
        }
        // next chunk's sT/sE writes are ordered after this fold by the
        // pack-side __syncthreads() of the next iteration.

        xlo = xlo_n; ylo = ylo_n; zlo = zlo_n; s = s_n;
    }

    if (seg == 0)
        out[b * (DVOX * DVOX) + i * DVOX + j] = 2.f * img - 1.f;
}

// ---------------------------------------------------------------------------
extern "C" void kernel_launch(void* const* d_in, const int* in_sizes, int n_in,
                              void* d_out, int out_size, void* d_ws, size_t ws_size,
                              hipStream_t stream) {
    const float* enc    = (const float*)d_in[0];
    const float* W      = (const float*)d_in[1];
    const float* bias   = (const float*)d_in[2];
    const float* angles = (const float*)d_in[3];
    float* out = (float*)d_out;

    char* ws = (char*)d_ws;
    unsigned short* encB = (unsigned short*)ws;           // 32 KB
    float* Rmat          = (float*)(ws + 32768);          // 2.3 KB
    __half* vox          = (__half*)(ws + 65536);         // 32 MiB

    prep_kernel<<<1, 256, 0, stream>>>(enc, angles, encB, Rmat);
    gemm_mfma_kernel<<<VOX / 256, 256, 0, stream>>>(encB, W, bias, vox);
    render_lds_kernel<<<BATCH * 64, 256, 0, stream>>>(vox, Rmat, out);
}

// Round 21
// 131.938 us; speedup vs baseline: 1.5300x; 1.0021x over previous
//
#include <hip/hip_runtime.h>
#include <hip/hip_bf16.h>
#include <hip/hip_fp16.h>
#include <math.h>

#define BATCH 64
#define LAT   256
#define DVOX  64
#define VOX   (DVOX*DVOX*DVOX)   // 262144

typedef __attribute__((ext_vector_type(8))) short short8;
typedef __attribute__((ext_vector_type(4))) float f32x4;
typedef unsigned uint32x4 __attribute__((ext_vector_type(4), aligned(4)));

// ---------------- kernel 0: enc -> bf16, build rotation matrices -----------
__global__ void prep_kernel(const float* __restrict__ enc,      // [64,256]
                            const float* __restrict__ angles,   // [64,3]
                            unsigned short* __restrict__ encB,  // [64,256] bf16 bits
                            float* __restrict__ Rmat) {         // [64,9]
    int tid = threadIdx.x;
    for (int idx = tid; idx < BATCH * LAT; idx += blockDim.x) {
        __hip_bfloat16 h = __float2bfloat16(enc[idx]);
        encB[idx] = *reinterpret_cast<unsigned short*>(&h);
    }
    if (tid < BATCH) {
        float ax = angles[tid*3+0], ay = angles[tid*3+1], az = angles[tid*3+2];
        float cx = cosf(ax), sx = sinf(ax);
        float cy = cosf(ay), sy = sinf(ay);
        float cz = cosf(az), sz = sinf(az);
        float* R = Rmat + tid * 9;
        R[0] = cz*cy;  R[1] = cz*sy*sx - sz*cx;  R[2] = cz*sy*cx + sz*sx;
        R[3] = sz*cy;  R[4] = sz*sy*sx + cz*cx;  R[5] = sz*sy*cx - cz*sx;
        R[6] = -sy;    R[7] = cy*sx;             R[8] = cy*cx;
    }
}

// ---------------- kernel 1: counted-vmcnt dbuf GEMM + NT|SC1 W-stream ------
// R20 + ONE change: W staging aux 2 -> 6 (NT | SC1). NT removed LLC
// insertion (-6.4 us); SC1 extends the no-allocate policy to the per-XCD
// L2 (~33 MB streamed/XCD vs 4 MB L2 = pure thrash, zero reuse: each W
// line is consumed by exactly one block on one XCD). Semantics unchanged.
#define LROW 260                         // dwords/row (256 + pad; +rotate<=24)
#define LBUF 8352                        // max write 8340 < 8352

__device__ __forceinline__ void gload_lds16_nt(const float* g, unsigned* l) {
    __builtin_amdgcn_global_load_lds(
        (__attribute__((address_space(1))) void*)(g),
        (__attribute__((address_space(3))) void*)(l),
        16, 0, 6);                        // aux=6: NT | SC1
}

__global__ __launch_bounds__(256) void gemm_mfma_kernel(
        const unsigned short* __restrict__ encB,  // [64,256] bf16
        const float* __restrict__ W,              // [256, 262144]
        const float* __restrict__ bias,           // [262144]
        __half* __restrict__ vox) {               // [64, 262144] fp16
    __shared__ unsigned lds[2 * LBUF];            // 66,816 B -> 2 blocks/CU

    int wave = threadIdx.x >> 6;
    int lane = threadIdx.x & 63;
    int l15 = lane & 15, l4 = lane >> 4;
    int n0 = blockIdx.x * 256;
    int n4 = n0 + wave * 64 + 4 * l15;

    const unsigned short* ap = encB + l15 * LAT + l4 * 8;
    const float* gb = W + n0 + lane * 4;

    f32x4 acc[4][4];
#pragma unroll
    for (int t = 0; t < 4; ++t)
#pragma unroll
        for (int mt = 0; mt < 4; ++mt) acc[t][mt] = (f32x4){0.f, 0.f, 0.f, 0.f};

    short8 a[2][4];                               // 2-slot A rotation

    auto loadA = [&](short8* as, int kb) {
#pragma unroll
        for (int mt = 0; mt < 4; ++mt)
            as[mt] = *(const short8*)(ap + mt * 16 * LAT + kb);   // 4 VMEM
    };
    auto stageW = [&](int buf, int kb) {
        unsigned* lb = lds + buf * LBUF;
#pragma unroll
        for (int i = 0; i < 8; ++i) {             // 8 VMEM (1 KB rows), NT|SC1
            int row = i * 4 + wave;
            gload_lds16_nt(gb + (size_t)(kb + row) * VOX,
                           lb + row * LROW + ((row >> 3) & 3) * 8);
        }
    };
    auto compute = [&](int buf, const short8* as) {
        const unsigned* lb = lds + buf * LBUF
                           + (l4 * 8) * LROW + l4 * 8
                           + wave * 64 + 4 * l15;
        uint4 dj[8];
#pragma unroll
        for (int j = 0; j < 8; ++j)
            dj[j] = *(const uint4*)(lb + j * LROW);
        short8 bf[4];
#pragma unroll
        for (int t = 0; t < 4; ++t) {
            unsigned bw[4];
#pragma unroll
            for (int dw = 0; dw < 4; ++dw) {
                unsigned u0 = ((const unsigned*)&dj[2 * dw])[t]     + 0x8000u;
                unsigned u1 = ((const unsigned*)&dj[2 * dw + 1])[t] + 0x8000u;
                bw[dw] = __builtin_amdgcn_perm(u1, u0, 0x07060302u);
            }
            bf[t] = *reinterpret_cast<short8*>(bw);
        }
#pragma unroll
        for (int t = 0; t < 4; ++t)
#pragma unroll
            for (int mt = 0; mt < 4; ++mt)
                acc[t][mt] = __builtin_amdgcn_mfma_f32_16x16x32_bf16(as[mt], bf[t], acc[t][mt], 0, 0, 0);
    };

    // prologue: tile 0 in flight
    loadA(a[0], 0);  stageW(0, 0);

#define KSTEP(kt, WAITSTR)                                        \
    {                                                             \
        if ((kt) + 1 < 8) {                                       \
            loadA(a[((kt) + 1) & 1], ((kt) + 1) * 32);            \
            stageW(((kt) + 1) & 1, ((kt) + 1) * 32);              \
        }                                                         \
        asm volatile(WAITSTR ::: "memory");                       \
        __builtin_amdgcn_sched_barrier(0);                        \
        __builtin_amdgcn_s_barrier();                             \
        __builtin_amdgcn_sched_barrier(0);                        \
        compute((kt) & 1, a[(kt) & 1]);                           \
        __builtin_amdgcn_s_barrier();                             \
    }

    KSTEP(0, "s_waitcnt vmcnt(12)")
    KSTEP(1, "s_waitcnt vmcnt(12)")
    KSTEP(2, "s_waitcnt vmcnt(12)")
    KSTEP(3, "s_waitcnt vmcnt(12)")
    KSTEP(4, "s_waitcnt vmcnt(12)")
    KSTEP(5, "s_waitcnt vmcnt(12)")
    KSTEP(6, "s_waitcnt vmcnt(12)")
    KSTEP(7, "s_waitcnt vmcnt(0)")
#undef KSTEP

    float4 bv = *(const float4*)(bias + n4);
#pragma unroll
    for (int mt = 0; mt < 4; ++mt) {
#pragma unroll
        for (int r = 0; r < 4; ++r) {
            int b = mt * 16 + l4 * 4 + r;
            float s[4];
#pragma unroll
            for (int t = 0; t < 4; ++t) {
                float x = acc[t][mt][r] + ((const float*)&bv)[t];
                float v = 1.f / (1.f + __expf(-x));   // sigmoid
                v = v * v; v = v * v; v = v * v;      // ^8
                s[t] = v;
            }
            __half2 h01 = __floats2half2_rn(s[0], s[1]);
            __half2 h23 = __floats2half2_rn(s[2], s[3]);
            uint2 pk;
            pk.x = *reinterpret_cast<unsigned*>(&h01);
            pk.y = *reinterpret_cast<unsigned*>(&h23);
            *reinterpret_cast<uint2*>(vox + (size_t)b * VOX + n4) = pk;
        }
    }
}

// ---------------- kernel 2: 4-wave cooperative LDS-brick resample ----------
// (exact round-12 build)
__device__ __forceinline__ float zlerp(unsigned e, float fz) {
    __half2 h = *reinterpret_cast<__half2*>(&e);
    float2 f = __half22float2(h);
    return f.x + (f.y - f.x) * fz;
}

__global__ __launch_bounds__(256) void render_lds_kernel(
        const __half* __restrict__ vox,   // [64, 262144] fp16
        const float* __restrict__ Rmat,   // [64,9]
        float* __restrict__ out) {        // [64,1,64,64]
    __shared__ unsigned sV[16 * 16 * 17]; // 17408 B brick, row stride 17
    __shared__ float sT[4][64], sE[4][64];

    int bid  = blockIdx.x;
    int b    = bid & 63;                  // bid%8 == b%8 -> XCD affinity
    int tile = bid >> 6;
    int t    = threadIdx.x;
    int pix  = t & 63, seg = t >> 6;      // seg == wave id
    int i0 = (tile >> 3) * 8, j0 = (tile & 7) * 8;
    int i = i0 + (pix >> 3);
    int j = j0 + (pix & 7);

    const float* Rb = Rmat + b * 9;       // uniform -> scalar loads
    float R0 = Rb[0], R1 = Rb[1], R2 = Rb[2];
    float R3 = Rb[3], R4 = Rb[4], R5 = Rb[5];
    float R6 = Rb[6], R7 = Rb[7], R8 = Rb[8];

    const float c = (DVOX - 1) * 0.5f;    // 31.5
    float di = (float)i - c, dj = (float)j - c;
    float xb = fmaf(R0, di, fmaf(R1, dj, c));
    float yb = fmaf(R3, di, fmaf(R4, dj, c));
    float zb = fmaf(R6, di, fmaf(R7, dj, c));

    float dic = (float)i0 + 3.5f - c;     // tile-center offsets (uniform)
    float djc = (float)j0 + 3.5f - c;
    float hwx = 3.5f * (fabsf(R0) + fabsf(R1) + fabsf(R2)) + 1e-3f;
    float hwy = 3.5f * (fabsf(R3) + fabsf(R4) + fabsf(R5)) + 1e-3f;
    float hwz = 3.5f * (fabsf(R6) + fabsf(R7) + fabsf(R8)) + 1e-3f;

    const unsigned short* V = (const unsigned short*)vox + (size_t)b * VOX;

    // this thread's staging row: x = t>>4, y = t&15
    int rx = t >> 4, ry = t & 15;
    unsigned d[9];
    int xlo_n, ylo_n, zlo_n, s_n;

    auto bbox = [&](int ch) {
        float dkc = (float)(ch * 8) + 3.5f - c;
        float xc = fmaf(R0, dic, fmaf(R1, djc, fmaf(R2, dkc, c)));
        float yc = fmaf(R3, dic, fmaf(R4, djc, fmaf(R5, dkc, c)));
        float zc = fmaf(R6, dic, fmaf(R7, djc, fmaf(R8, dkc, c)));
        xlo_n = (int)floorf(xc - hwx);
        ylo_n = (int)floorf(yc - hwy);
        zlo_n = (int)floorf(zc - hwz);
        s_n   = zlo_n & ~1;
    };
    auto issue = [&]() {
        int gxc = min(max(xlo_n + rx, 0), DVOX - 1);
        int gyc = min(max(ylo_n + ry, 0), DVOX - 1);
        const unsigned* p = (const unsigned*)(V + ((gxc << 12) + (gyc << 6) + s_n));
        uint32x4 q0 = *(const uint32x4*)p;        // dwordx4 (4B-align ok)
        uint32x4 q1 = *(const uint32x4*)(p + 4);
        unsigned q2 = p[8];
        d[0] = q0[0]; d[1] = q0[1]; d[2] = q0[2]; d[3] = q0[3];
        d[4] = q1[0]; d[5] = q1[1]; d[6] = q1[2]; d[7] = q1[3];
        d[8] = q2;
    };

    bbox(7); issue();
    int xlo = xlo_n, ylo = ylo_n, zlo = zlo_n, s = s_n;

    float img = 0.f;                      // live in wave 0 only
#pragma unroll 1
    for (int ch = 7; ch >= 0; --ch) {     // back-to-front chunks of 8 z
        bool zint = (zlo >= 0) && (zlo + 17 <= DVOX);

        // ---- pack this thread's row into the brick ------------------------
        {
            bool rv = ((unsigned)(xlo + rx) < (unsigned)DVOX) &
                      ((unsigned)(ylo + ry) < (unsigned)DVOX);
            unsigned tt[9];
#pragma unroll
            for (int k = 0; k < 9; ++k) tt[k] = d[k];
            if (!zint) {                  // block-uniform branch
#pragma unroll
                for (int k = 0; k < 9; ++k) {
                    int h0 = s + 2 * k;
                    unsigned m = (((unsigned)h0 < (unsigned)DVOX) ? 0x0000FFFFu : 0u)
                               | (((unsigned)(h0 + 1) < (unsigned)DVOX) ? 0xFFFF0000u : 0u);
                    tt[k] &= m;
                }
            }
            unsigned rvm = rv ? 0xFFFFFFFFu : 0u;
#pragma unroll
            for (int k = 0; k < 9; ++k) tt[k] &= rvm;

            unsigned A[8];
#pragma unroll
            for (int m = 0; m < 8; ++m)
                A[m] = (tt[m] >> 16) | (tt[m + 1] << 16);   // v_alignbit

            unsigned* wrow = sV + t * 17;
            if (zlo & 1) {                // block-uniform
#pragma unroll
                for (int m = 0; m < 8; ++m) {
                    wrow[2 * m]     = A[m];
                    wrow[2 * m + 1] = tt[m + 1];
                }
            } else {
#pragma unroll
                for (int m = 0; m < 8; ++m) {
                    wrow[2 * m]     = tt[m];
                    wrow[2 * m + 1] = A[m];
                }
            }
        }
        __syncthreads();

        // ---- issue NEXT chunk's loads (latency hides under sampling) ------
        if (ch > 0) { bbox(ch - 1); issue(); }

        // ---- sample this wave's 2-z segment, back-to-front ----------------
        float T = 1.f, E = 0.f;
        int k0 = ch * 8;
#pragma unroll
        for (int q = 1; q >= 0; --q) {    // kk = 2*seg+1, then 2*seg
            int kk = 2 * seg + q;
            float dk = (float)(k0 + kk) - c;
            float x = fmaf(R2, dk, xb);
            float y = fmaf(R5, dk, yb);
            float z = fmaf(R8, dk, zb);

            float xf = floorf(x), yf = floorf(y), zf = floorf(z);
            float fx = x - xf, fy = y - yf, fz = z - zf;
            int xi = (int)xf - xlo;       // [0,14]
            int yi = (int)yf - ylo;
            int zi = (int)zf - zlo;
            const unsigned* e = sV + (xi * 272 + yi * 17 + zi);

            float c00 = zlerp(e[0],   fz);   // (x0,y0)
            float c01 = zlerp(e[17],  fz);   // (x0,y1)
            float c10 = zlerp(e[272], fz);   // (x1,y0)
            float c11 = zlerp(e[289], fz);   // (x1,y1)
            float c0 = c00 + (c01 - c00) * fy;
            float c1 = c10 + (c11 - c10) * fy;
            float a  = c0  + (c1  - c0 ) * fx;

            E = E * (1.f - a) + a;
            T *= (1.f - a);
        }
        sT[seg][pix] = T;
        sE[seg][pix] = E;
        __syncthreads();

        // ---- wave 0 folds the 4 segments (back seg 3 first) ---------------
        if (seg == 0) {
            float im = img;
#pragma unroll
            for (int ss = 3; ss >= 0; --ss)
                im = fmaf(sT[ss][pix], im, sE[ss][pix]);
            img = im;
        }
        // next chunk's sT/sE writes are ordered after this fold by the
        // pack-side __syncthreads() of the next iteration.

        xlo = xlo_n; ylo = ylo_n; zlo = zlo_n; s = s_n;
    }

    if (seg == 0)
        out[b * (DVOX * DVOX) + i * DVOX + j] = 2.f * img - 1.f;
}

// ---------------------------------------------------------------------------
extern "C" void kernel_launch(void* const* d_in, const int* in_sizes, int n_in,
                              void* d_out, int out_size, void* d_ws, size_t ws_size,
                              hipStream_t stream) {
    const float* enc    = (const float*)d_in[0];
    const float* W      = (const float*)d_in[1];
    const float* bias   = (const float*)d_in[2];
    const float* angles = (const float*)d_in[3];
    float* out = (float*)d_out;

    char* ws = (char*)d_ws;
    unsigned short* encB = (unsigned short*)ws;           // 32 KB
    float* Rmat          = (float*)(ws + 32768);          // 2.3 KB
    __half* vox          = (__half*)(ws + 65536);         // 32 MiB

    prep_kernel<<<1, 256, 0, stream>>>(enc, angles, encB, Rmat);
    gemm_mfma_kernel<<<VOX / 256, 256, 0, stream>>>(encB, W, bias, vox);
    render_lds_kernel<<<BATCH * 64, 256, 0, stream>>>(vox, Rmat, out);
}

// Round 22
// 120.458 us; speedup vs baseline: 1.6758x; 1.0953x over previous
//
#include <hip/hip_runtime.h>
#include <hip/hip_bf16.h>
#include <hip/hip_fp16.h>
#include <math.h>

#define BATCH 64
#define LAT   256
#define DVOX  64
#define VOX   (DVOX*DVOX*DVOX)   // 262144

typedef __attribute__((ext_vector_type(8))) short short8;
typedef __attribute__((ext_vector_type(4))) float f32x4;
typedef unsigned uint32x4 __attribute__((ext_vector_type(4), aligned(4)));

// ---------------- kernel 1: counted-vmcnt dbuf GEMM (prep merged) ----------
// R21 structure + prep deleted: A is loaded RAW fp32 from enc (8 VMEM/tile,
// issued ahead of the W stage; 64 KB enc is L2-hot) and converted to bf16
// inside compute() AFTER the counted wait — no extra drain. Per tile:
// 8 A-loads + 8 W-stages = 16 VMEM; steady-state wait = vmcnt(16) (tile kt
// retired, tile kt+1 fully in flight across the barrier). W staging keeps
// aux=6 (NT|SC1) from R20/21 (-6.4 us).
#define LROW 260                         // dwords/row (256 + pad; +rotate<=24)
#define LBUF 8352                        // max write 8340 < 8352

__device__ __forceinline__ void gload_lds16_nt(const float* g, unsigned* l) {
    __builtin_amdgcn_global_load_lds(
        (__attribute__((address_space(1))) void*)(g),
        (__attribute__((address_space(3))) void*)(l),
        16, 0, 6);                        // aux=6: NT | SC1
}

__global__ __launch_bounds__(256) void gemm_mfma_kernel(
        const float* __restrict__ enc,            // [64,256] fp32
        const float* __restrict__ W,              // [256, 262144]
        const float* __restrict__ bias,           // [262144]
        __half* __restrict__ vox) {               // [64, 262144] fp16
    __shared__ unsigned lds[2 * LBUF];            // 66,816 B -> 2 blocks/CU

    int wave = threadIdx.x >> 6;
    int lane = threadIdx.x & 63;
    int l15 = lane & 15, l4 = lane >> 4;
    int n0 = blockIdx.x * 256;
    int n4 = n0 + wave * 64 + 4 * l15;

    const float* ap = enc + l15 * LAT + l4 * 8;   // A source (fp32)
    const float* gb = W + n0 + lane * 4;

    f32x4 acc[4][4];
#pragma unroll
    for (int t = 0; t < 4; ++t)
#pragma unroll
        for (int mt = 0; mt < 4; ++mt) acc[t][mt] = (f32x4){0.f, 0.f, 0.f, 0.f};

    float4 af[2][8];                              // raw fp32 A, 2-slot rotation

    auto loadA = [&](int slot, int kb) {
#pragma unroll
        for (int mt = 0; mt < 4; ++mt) {          // 8 VMEM (2 dwordx4 / frag)
            af[slot][2 * mt]     = *(const float4*)(ap + mt * 16 * LAT + kb);
            af[slot][2 * mt + 1] = *(const float4*)(ap + mt * 16 * LAT + kb + 4);
        }
    };
    auto stageW = [&](int buf, int kb) {
        unsigned* lb = lds + buf * LBUF;
#pragma unroll
        for (int i = 0; i < 8; ++i) {             // 8 VMEM (1 KB rows), NT|SC1
            int row = i * 4 + wave;
            gload_lds16_nt(gb + (size_t)(kb + row) * VOX,
                           lb + row * LROW + ((row >> 3) & 3) * 8);
        }
    };
    auto compute = [&](int buf, int slot) {
        // A: fp32 -> bf16 pack (post-waitcnt, validated +0x8000 + v_perm)
        short8 a[4];
#pragma unroll
        for (int mt = 0; mt < 4; ++mt) {
            unsigned aw[4];
#pragma unroll
            for (int h = 0; h < 2; ++h) {
                const float4& v = af[slot][2 * mt + h];
                unsigned u0 = __float_as_uint(v.x) + 0x8000u;
                unsigned u1 = __float_as_uint(v.y) + 0x8000u;
                unsigned u2 = __float_as_uint(v.z) + 0x8000u;
                unsigned u3 = __float_as_uint(v.w) + 0x8000u;
                aw[2 * h]     = __builtin_amdgcn_perm(u1, u0, 0x07060302u);
                aw[2 * h + 1] = __builtin_amdgcn_perm(u3, u2, 0x07060302u);
            }
            a[mt] = *reinterpret_cast<short8*>(aw);
        }
        const unsigned* lb = lds + buf * LBUF
                           + (l4 * 8) * LROW + l4 * 8
                           + wave * 64 + 4 * l15;
        uint4 dj[8];
#pragma unroll
        for (int j = 0; j < 8; ++j)
            dj[j] = *(const uint4*)(lb + j * LROW);
        short8 bf[4];
#pragma unroll
        for (int t = 0; t < 4; ++t) {
            unsigned bw[4];
#pragma unroll
            for (int dw = 0; dw < 4; ++dw) {
                unsigned u0 = ((const unsigned*)&dj[2 * dw])[t]     + 0x8000u;
                unsigned u1 = ((const unsigned*)&dj[2 * dw + 1])[t] + 0x8000u;
                bw[dw] = __builtin_amdgcn_perm(u1, u0, 0x07060302u);
            }
            bf[t] = *reinterpret_cast<short8*>(bw);
        }
#pragma unroll
        for (int t = 0; t < 4; ++t)
#pragma unroll
            for (int mt = 0; mt < 4; ++mt)
                acc[t][mt] = __builtin_amdgcn_mfma_f32_16x16x32_bf16(a[mt], bf[t], acc[t][mt], 0, 0, 0);
    };

    // prologue: tile 0 in flight (A before W)
    loadA(0, 0);  stageW(0, 0);

#define KSTEP(kt, WAITSTR)                                        \
    {                                                             \
        if ((kt) + 1 < 8) {                                       \
            loadA(((kt) + 1) & 1, ((kt) + 1) * 32);               \
            stageW(((kt) + 1) & 1, ((kt) + 1) * 32);              \
        }                                                         \
        asm volatile(WAITSTR ::: "memory");                       \
        __builtin_amdgcn_sched_barrier(0);                        \
        __builtin_amdgcn_s_barrier();                             \
        __builtin_amdgcn_sched_barrier(0);                        \
        compute((kt) & 1, (kt) & 1);                              \
        __builtin_amdgcn_s_barrier();                             \
    }

    KSTEP(0, "s_waitcnt vmcnt(16)")
    KSTEP(1, "s_waitcnt vmcnt(16)")
    KSTEP(2, "s_waitcnt vmcnt(16)")
    KSTEP(3, "s_waitcnt vmcnt(16)")
    KSTEP(4, "s_waitcnt vmcnt(16)")
    KSTEP(5, "s_waitcnt vmcnt(16)")
    KSTEP(6, "s_waitcnt vmcnt(16)")
    KSTEP(7, "s_waitcnt vmcnt(0)")
#undef KSTEP

    float4 bv = *(const float4*)(bias + n4);
#pragma unroll
    for (int mt = 0; mt < 4; ++mt) {
#pragma unroll
        for (int r = 0; r < 4; ++r) {
            int b = mt * 16 + l4 * 4 + r;
            float s[4];
#pragma unroll
            for (int t = 0; t < 4; ++t) {
                float x = acc[t][mt][r] + ((const float*)&bv)[t];
                float v = 1.f / (1.f + __expf(-x));   // sigmoid
                v = v * v; v = v * v; v = v * v;      // ^8
                s[t] = v;
            }
            __half2 h01 = __floats2half2_rn(s[0], s[1]);
            __half2 h23 = __floats2half2_rn(s[2], s[3]);
            uint2 pk;
            pk.x = *reinterpret_cast<unsigned*>(&h01);
            pk.y = *reinterpret_cast<unsigned*>(&h23);
            *reinterpret_cast<uint2*>(vox + (size_t)b * VOX + n4) = pk;
        }
    }
}

// ---------------- kernel 2: 4-wave cooperative LDS-brick resample ----------
// R21 structure; R matrix computed in-kernel from angles (wave-uniform,
// validated in R18 phase B) — prep kernel deleted.
__device__ __forceinline__ float zlerp(unsigned e, float fz) {
    __half2 h = *reinterpret_cast<__half2*>(&e);
    float2 f = __half22float2(h);
    return f.x + (f.y - f.x) * fz;
}

__global__ __launch_bounds__(256) void render_lds_kernel(
        const __half* __restrict__ vox,   // [64, 262144] fp16
        const float* __restrict__ angles, // [64,3]
        float* __restrict__ out) {        // [64,1,64,64]
    __shared__ unsigned sV[16 * 16 * 17]; // 17408 B brick, row stride 17
    __shared__ float sT[4][64], sE[4][64];

    int bid  = blockIdx.x;
    int b    = bid & 63;                  // bid%8 == b%8 -> XCD affinity
    int tile = bid >> 6;
    int t    = threadIdx.x;
    int pix  = t & 63, seg = t >> 6;      // seg == wave id
    int i0 = (tile >> 3) * 8, j0 = (tile & 7) * 8;
    int i = i0 + (pix >> 3);
    int j = j0 + (pix & 7);

    float ax = angles[b*3+0], ay = angles[b*3+1], az = angles[b*3+2];
    float cx = cosf(ax), sx = sinf(ax);
    float cy = cosf(ay), sy = sinf(ay);
    float cz = cosf(az), sz = sinf(az);
    float R0 = cz*cy, R1 = cz*sy*sx - sz*cx, R2 = cz*sy*cx + sz*sx;
    float R3 = sz*cy, R4 = sz*sy*sx + cz*cx, R5 = sz*sy*cx - cz*sx;
    float R6 = -sy,   R7 = cy*sx,            R8 = cy*cx;

    const float c = (DVOX - 1) * 0.5f;    // 31.5
    float di = (float)i - c, dj = (float)j - c;
    float xb = fmaf(R0, di, fmaf(R1, dj, c));
    float yb = fmaf(R3, di, fmaf(R4, dj, c));
    float zb = fmaf(R6, di, fmaf(R7, dj, c));

    float dic = (float)i0 + 3.5f - c;     // tile-center offsets (uniform)
    float djc = (float)j0 + 3.5f - c;
    float hwx = 3.5f * (fabsf(R0) + fabsf(R1) + fabsf(R2)) + 1e-3f;
    float hwy = 3.5f * (fabsf(R3) + fabsf(R4) + fabsf(R5)) + 1e-3f;
    float hwz = 3.5f * (fabsf(R6) + fabsf(R7) + fabsf(R8)) + 1e-3f;

    const unsigned short* V = (const unsigned short*)vox + (size_t)b * VOX;

    // this thread's staging row: x = t>>4, y = t&15
    int rx = t >> 4, ry = t & 15;
    unsigned d[9];
    int xlo_n, ylo_n, zlo_n, s_n;

    auto bbox = [&](int ch) {
        float dkc = (float)(ch * 8) + 3.5f - c;
        float xc = fmaf(R0, dic, fmaf(R1, djc, fmaf(R2, dkc, c)));
        float yc = fmaf(R3, dic, fmaf(R4, djc, fmaf(R5, dkc, c)));
        float zc = fmaf(R6, dic, fmaf(R7, djc, fmaf(R8, dkc, c)));
        xlo_n = (int)floorf(xc - hwx);
        ylo_n = (int)floorf(yc - hwy);
        zlo_n = (int)floorf(zc - hwz);
        s_n   = zlo_n & ~1;
    };
    auto issue = [&]() {
        int gxc = min(max(xlo_n + rx, 0), DVOX - 1);
        int gyc = min(max(ylo_n + ry, 0), DVOX - 1);
        const unsigned* p = (const unsigned*)(V + ((gxc << 12) + (gyc << 6) + s_n));
        uint32x4 q0 = *(const uint32x4*)p;        // dwordx4 (4B-align ok)
        uint32x4 q1 = *(const uint32x4*)(p + 4);
        unsigned q2 = p[8];
        d[0] = q0[0]; d[1] = q0[1]; d[2] = q0[2]; d[3] = q0[3];
        d[4] = q1[0]; d[5] = q1[1]; d[6] = q1[2]; d[7] = q1[3];
        d[8] = q2;
    };

    bbox(7); issue();
    int xlo = xlo_n, ylo = ylo_n, zlo = zlo_n, s = s_n;

    float img = 0.f;                      // live in wave 0 only
#pragma unroll 1
    for (int ch = 7; ch >= 0; --ch) {     // back-to-front chunks of 8 z
        bool zint = (zlo >= 0) && (zlo + 17 <= DVOX);

        // ---- pack this thread's row into the brick ------------------------
        {
            bool rv = ((unsigned)(xlo + rx) < (unsigned)DVOX) &
                      ((unsigned)(ylo + ry) < (unsigned)DVOX);
            unsigned tt[9];
#pragma unroll
            for (int k = 0; k < 9; ++k) tt[k] = d[k];
            if (!zint) {                  // block-uniform branch
#pragma unroll
                for (int k = 0; k < 9; ++k) {
                    int h0 = s + 2 * k;
                    unsigned m = (((unsigned)h0 < (unsigned)DVOX) ? 0x0000FFFFu : 0u)
                               | (((unsigned)(h0 + 1) < (unsigned)DVOX) ? 0xFFFF0000u : 0u);
                    tt[k] &= m;
                }
            }
            unsigned rvm = rv ? 0xFFFFFFFFu : 0u;
#pragma unroll
            for (int k = 0; k < 9; ++k) tt[k] &= rvm;

            unsigned A[8];
#pragma unroll
            for (int m = 0; m < 8; ++m)
                A[m] = (tt[m] >> 16) | (tt[m + 1] << 16);   // v_alignbit

            unsigned* wrow = sV + t * 17;
            if (zlo & 1) {                // block-uniform
#pragma unroll
                for (int m = 0; m < 8; ++m) {
                    wrow[2 * m]     = A[m];
                    wrow[2 * m + 1] = tt[m + 1];
                }
            } else {
#pragma unroll
                for (int m = 0; m < 8; ++m) {
                    wrow[2 * m]     = tt[m];
                    wrow[2 * m + 1] = A[m];
                }
            }
        }
        __syncthreads();

        // ---- issue NEXT chunk's loads (latency hides under sampling) ------
        if (ch > 0) { bbox(ch - 1); issue(); }

        // ---- sample this wave's 2-z segment, back-to-front ----------------
        float T = 1.f, E = 0.f;
        int k0 = ch * 8;
#pragma unroll
        for (int q = 1; q >= 0; --q) {    // kk = 2*seg+1, then 2*seg
            int kk = 2 * seg + q;
            float dk = (float)(k0 + kk) - c;
            float x = fmaf(R2, dk, xb);
            float y = fmaf(R5, dk, yb);
            float z = fmaf(R8, dk, zb);

            float xf = floorf(x), yf = floorf(y), zf = floorf(z);
            float fx = x - xf, fy = y - yf, fz = z - zf;
            int xi = (int)xf - xlo;       // [0,14]
            int yi = (int)yf - ylo;
            int zi = (int)zf - zlo;
            const unsigned* e = sV + (xi * 272 + yi * 17 + zi);

            float c00 = zlerp(e[0],   fz);   // (x0,y0)
            float c01 = zlerp(e[17],  fz);   // (x0,y1)
            float c10 = zlerp(e[272], fz);   // (x1,y0)
            float c11 = zlerp(e[289], fz);   // (x1,y1)
            float c0 = c00 + (c01 - c00) * fy;
            float c1 = c10 + (c11 - c10) * fy;
            float a  = c0  + (c1  - c0 ) * fx;

            E = E * (1.f - a) + a;
            T *= (1.f - a);
        }
        sT[seg][pix] = T;
        sE[seg][pix] = E;
        __syncthreads();

        // ---- wave 0 folds the 4 segments (back seg 3 first) ---------------
        if (seg == 0) {
            float im = img;
#pragma unroll
            for (int ss = 3; ss >= 0; --ss)
                im = fmaf(sT[ss][pix], im, sE[ss][pix]);
            img = im;
        }
        // next chunk's sT/sE writes are ordered after this fold by the
        // pack-side __syncthreads() of the next iteration.

        xlo = xlo_n; ylo = ylo_n; zlo = zlo_n; s = s_n;
    }

    if (seg == 0)
        out[b * (DVOX * DVOX) + i * DVOX + j] = 2.f * img - 1.f;
}

// ---------------------------------------------------------------------------
extern "C" void kernel_launch(void* const* d_in, const int* in_sizes, int n_in,
                              void* d_out, int out_size, void* d_ws, size_t ws_size,
                              hipStream_t stream) {
    const float* enc    = (const float*)d_in[0];
    const float* W      = (const float*)d_in[1];
    const float* bias   = (const float*)d_in[2];
    const float* angles = (const float*)d_in[3];
    float* out = (float*)d_out;

    char* ws = (char*)d_ws;
    __half* vox = (__half*)(ws + 65536);          // 32 MiB

    gemm_mfma_kernel<<<VOX / 256, 256, 0, stream>>>(enc, W, bias, vox);
    render_lds_kernel<<<BATCH * 64, 256, 0, stream>>>(vox, angles, out);
}